// Round 1
// baseline (2625.728 us; speedup 1.0000x reference)
//
#include <hip/hip_runtime.h>
#include <cstdint>

#define D 128
#define H 4
#define N_ENT 100000
#define N_EDGE 400000

// ---------------------------------------------------------------------------
// K1: Q = entity_emb @ qTrans        (Q is stored in d_out, consumed by K2)
// Block: 512 threads, 128 nodes per block.
// LDS: qT (64KB) + transposed node rows (64KB). Thread = (jj: 8 cols, ee: 4 rows).
// ---------------------------------------------------------------------------
__global__ __launch_bounds__(512) void k_qproj(const float* __restrict__ ent,
                                               const float* __restrict__ qT,
                                               float* __restrict__ Q) {
  __shared__ float sT[D * D];      // qT[i][j]
  __shared__ float rows[D * 128];  // rows[i][n]  (transposed)
  const int t = threadIdx.x;
  const int n0 = blockIdx.x * 128;
#pragma unroll
  for (int s = 0; s < 8; ++s) {
    const int idx = (s * 512 + t) * 4;
    *(float4*)&sT[idx] = *(const float4*)&qT[idx];
  }
  {
    const int g = t & 3;       // 0..3: quarter of the row
    const int n = t >> 2;      // 0..127: local node
    const int node = n0 + n;
    if (node < N_ENT) {
      const float* src = ent + (size_t)node * D;
#pragma unroll
      for (int s = 0; s < 8; ++s) {
        const int i = s * 16 + g * 4;
        float4 v = *(const float4*)&src[i];
        rows[(i + 0) * 128 + n] = v.x;
        rows[(i + 1) * 128 + n] = v.y;
        rows[(i + 2) * 128 + n] = v.z;
        rows[(i + 3) * 128 + n] = v.w;
      }
    } else {
#pragma unroll
      for (int s = 0; s < 8; ++s) {
        const int i = s * 16 + g * 4;
        rows[(i + 0) * 128 + n] = 0.f;
        rows[(i + 1) * 128 + n] = 0.f;
        rows[(i + 2) * 128 + n] = 0.f;
        rows[(i + 3) * 128 + n] = 0.f;
      }
    }
  }
  __syncthreads();
  const int jj = t & 15;   // cols jj*8 .. jj*8+7
  const int ee = t >> 4;   // nodes ee*4 .. ee*4+3
  float acc[4][8];
#pragma unroll
  for (int a = 0; a < 4; ++a)
#pragma unroll
    for (int b = 0; b < 8; ++b) acc[a][b] = 0.f;
#pragma unroll 4
  for (int i = 0; i < D; ++i) {
    float4 b0 = *(float4*)&sT[i * D + jj * 8];
    float4 b1 = *(float4*)&sT[i * D + jj * 8 + 4];
    float4 a0 = *(float4*)&rows[i * 128 + ee * 4];
    float bv[8] = {b0.x, b0.y, b0.z, b0.w, b1.x, b1.y, b1.z, b1.w};
    float av[4] = {a0.x, a0.y, a0.z, a0.w};
#pragma unroll
    for (int a = 0; a < 4; ++a)
#pragma unroll
      for (int b = 0; b < 8; ++b) acc[a][b] = fmaf(av[a], bv[b], acc[a][b]);
  }
#pragma unroll
  for (int a = 0; a < 4; ++a) {
    const int node = n0 + ee * 4 + a;
    if (node < N_ENT) {
      float4 o0 = {acc[a][0], acc[a][1], acc[a][2], acc[a][3]};
      float4 o1 = {acc[a][4], acc[a][5], acc[a][6], acc[a][7]};
      *(float4*)&Q[(size_t)node * D + jj * 8] = o0;
      *(float4*)&Q[(size_t)node * D + jj * 8 + 4] = o1;
    }
  }
}

// ---------------------------------------------------------------------------
// K2: per-edge attention logits.
//   neigh = ent[tail] * rel;  k = neigh @ kT;  att[h] = clip(q_h . k_h);
//   exp_att stored; atomicAdd into attnorm[head,h].
// Block: 512 threads, 128 edges per block. Same GEMM layout as K1.
// Head of col group: h = jj>>2 (cols jj*8..+7 all lie in head jj/4).
// ---------------------------------------------------------------------------
__global__ __launch_bounds__(512) void k_attlogit(
    const float* __restrict__ ent, const float* __restrict__ wrel,
    const float* __restrict__ kT, const float* __restrict__ Q,
    const int* __restrict__ head, const int* __restrict__ tail,
    const int* __restrict__ etype, float* __restrict__ expatt,
    float* __restrict__ attnorm) {
  __shared__ float sT[D * D];
  __shared__ float neigh[D * 128];  // neigh[i][e]
  __shared__ int sh[128];
  const int t = threadIdx.x;
  const int e0 = blockIdx.x * 128;
#pragma unroll
  for (int s = 0; s < 8; ++s) {
    const int idx = (s * 512 + t) * 4;
    *(float4*)&sT[idx] = *(const float4*)&kT[idx];
  }
  if (t < 128) sh[t] = head[e0 + t];
  {
    const int g = t & 3;
    const int le = t >> 2;
    const int tl = tail[e0 + le];
    const int ty = etype[e0 + le] - 1;
    const float* src = ent + (size_t)tl * D;
    const float* rl = wrel + (size_t)ty * D;
#pragma unroll
    for (int s = 0; s < 8; ++s) {
      const int i = s * 16 + g * 4;
      float4 v = *(const float4*)&src[i];
      float4 r = *(const float4*)&rl[i];
      neigh[(i + 0) * 128 + le] = v.x * r.x;
      neigh[(i + 1) * 128 + le] = v.y * r.y;
      neigh[(i + 2) * 128 + le] = v.z * r.z;
      neigh[(i + 3) * 128 + le] = v.w * r.w;
    }
  }
  __syncthreads();
  const int jj = t & 15;
  const int ee = t >> 4;
  float acc[4][8];
#pragma unroll
  for (int a = 0; a < 4; ++a)
#pragma unroll
    for (int b = 0; b < 8; ++b) acc[a][b] = 0.f;
#pragma unroll 4
  for (int i = 0; i < D; ++i) {
    float4 b0 = *(float4*)&sT[i * D + jj * 8];
    float4 b1 = *(float4*)&sT[i * D + jj * 8 + 4];
    float4 a0 = *(float4*)&neigh[i * 128 + ee * 4];
    float bv[8] = {b0.x, b0.y, b0.z, b0.w, b1.x, b1.y, b1.z, b1.w};
    float av[4] = {a0.x, a0.y, a0.z, a0.w};
#pragma unroll
    for (int a = 0; a < 4; ++a)
#pragma unroll
      for (int b = 0; b < 8; ++b) acc[a][b] = fmaf(av[a], bv[b], acc[a][b]);
  }
  const int h = jj >> 2;
#pragma unroll
  for (int a = 0; a < 4; ++a) {
    const int le = ee * 4 + a;
    const int hd = sh[le];
    const float* qrow = Q + (size_t)hd * D + jj * 8;
    float4 q0 = *(const float4*)&qrow[0];
    float4 q1 = *(const float4*)&qrow[4];
    float p = q0.x * acc[a][0] + q0.y * acc[a][1] + q0.z * acc[a][2] +
              q0.w * acc[a][3] + q1.x * acc[a][4] + q1.y * acc[a][5] +
              q1.z * acc[a][6] + q1.w * acc[a][7];
    p += __shfl_xor(p, 1);
    p += __shfl_xor(p, 2);
    if ((jj & 3) == 0) {
      float att = fminf(fmaxf(p, -10.f), 10.f);
      float ex = expf(att);
      expatt[(size_t)(e0 + le) * H + h] = ex;
      atomicAdd(&attnorm[(size_t)hd * H + h], ex);
    }
  }
}

// ---------------------------------------------------------------------------
// K3: v = neigh @ vT; att = expatt/(norm+1e-8); kg[head] += att[h]*v (atomic)
// ---------------------------------------------------------------------------
__global__ __launch_bounds__(512) void k_vagg(
    const float* __restrict__ ent, const float* __restrict__ wrel,
    const float* __restrict__ vT, const int* __restrict__ head,
    const int* __restrict__ tail, const int* __restrict__ etype,
    const float* __restrict__ expatt, const float* __restrict__ attnorm,
    float* __restrict__ kg) {
  __shared__ float sT[D * D];
  __shared__ float neigh[D * 128];
  __shared__ int sh[128];
  const int t = threadIdx.x;
  const int e0 = blockIdx.x * 128;
#pragma unroll
  for (int s = 0; s < 8; ++s) {
    const int idx = (s * 512 + t) * 4;
    *(float4*)&sT[idx] = *(const float4*)&vT[idx];
  }
  if (t < 128) sh[t] = head[e0 + t];
  {
    const int g = t & 3;
    const int le = t >> 2;
    const int tl = tail[e0 + le];
    const int ty = etype[e0 + le] - 1;
    const float* src = ent + (size_t)tl * D;
    const float* rl = wrel + (size_t)ty * D;
#pragma unroll
    for (int s = 0; s < 8; ++s) {
      const int i = s * 16 + g * 4;
      float4 v = *(const float4*)&src[i];
      float4 r = *(const float4*)&rl[i];
      neigh[(i + 0) * 128 + le] = v.x * r.x;
      neigh[(i + 1) * 128 + le] = v.y * r.y;
      neigh[(i + 2) * 128 + le] = v.z * r.z;
      neigh[(i + 3) * 128 + le] = v.w * r.w;
    }
  }
  __syncthreads();
  const int jj = t & 15;
  const int ee = t >> 4;
  float acc[4][8];
#pragma unroll
  for (int a = 0; a < 4; ++a)
#pragma unroll
    for (int b = 0; b < 8; ++b) acc[a][b] = 0.f;
#pragma unroll 4
  for (int i = 0; i < D; ++i) {
    float4 b0 = *(float4*)&sT[i * D + jj * 8];
    float4 b1 = *(float4*)&sT[i * D + jj * 8 + 4];
    float4 a0 = *(float4*)&neigh[i * 128 + ee * 4];
    float bv[8] = {b0.x, b0.y, b0.z, b0.w, b1.x, b1.y, b1.z, b1.w};
    float av[4] = {a0.x, a0.y, a0.z, a0.w};
#pragma unroll
    for (int a = 0; a < 4; ++a)
#pragma unroll
      for (int b = 0; b < 8; ++b) acc[a][b] = fmaf(av[a], bv[b], acc[a][b]);
  }
  const int h = jj >> 2;
#pragma unroll
  for (int a = 0; a < 4; ++a) {
    const int le = ee * 4 + a;
    const int hd = sh[le];
    const float an = attnorm[(size_t)hd * H + h] + 1e-8f;
    const float at = expatt[(size_t)(e0 + le) * H + h] / an;
    float* dst = kg + (size_t)hd * D + jj * 8;
#pragma unroll
    for (int c = 0; c < 8; ++c) atomicAdd(&dst[c], at * acc[a][c]);
  }
}

// ---------------------------------------------------------------------------
// K4: w[e] = (||kg[head]*rel|| * ||kg[tail]*rel||)^2 = S_h * S_t (no sqrt);
//     atomicMax mvec[head] (uint trick; w >= 0 always).
// 32 lanes per edge, 8 edges per 256-thread block.
// ---------------------------------------------------------------------------
__global__ __launch_bounds__(256) void k_w(
    const float* __restrict__ kg, const float* __restrict__ wrel,
    const int* __restrict__ head, const int* __restrict__ tail,
    const int* __restrict__ etype, float* __restrict__ wvec,
    unsigned int* __restrict__ mvec) {
  const int t = threadIdx.x;
  const int lane = t & 31;
  const int le = t >> 5;
  const int e = blockIdx.x * 8 + le;
  if (e >= N_EDGE) return;
  const int hd = head[e], tl = tail[e], ty = etype[e] - 1;
  float4 r = *(const float4*)&wrel[(size_t)ty * D + lane * 4];
  float4 a = *(const float4*)&kg[(size_t)hd * D + lane * 4];
  float4 b = *(const float4*)&kg[(size_t)tl * D + lane * 4];
  float hx = a.x * r.x, hy = a.y * r.y, hz = a.z * r.z, hw = a.w * r.w;
  float tx = b.x * r.x, ty2 = b.y * r.y, tz = b.z * r.z, tw = b.w * r.w;
  float sh_ = hx * hx + hy * hy + hz * hz + hw * hw;
  float st_ = tx * tx + ty2 * ty2 + tz * tz + tw * tw;
#pragma unroll
  for (int o = 16; o > 0; o >>= 1) {
    sh_ += __shfl_xor(sh_, o);
    st_ += __shfl_xor(st_, o);
  }
  if (lane == 0) {
    float w = sh_ * st_;
    wvec[e] = w;
    atomicMax(&mvec[hd], __float_as_uint(w));
  }
}

// ---------------------------------------------------------------------------
// K5: evec[e] = exp(w - m[head]);  atomicAdd svec[head].
// ---------------------------------------------------------------------------
__global__ __launch_bounds__(256) void k_expw(
    const int* __restrict__ head, const float* __restrict__ wvec,
    const unsigned int* __restrict__ mvec, float* __restrict__ evec,
    float* __restrict__ svec) {
  const int e = blockIdx.x * 256 + threadIdx.x;
  if (e >= N_EDGE) return;
  const int hd = head[e];
  const float m = __uint_as_float(mvec[hd]);
  const float ex = expf(wvec[e] - m);
  evec[e] = ex;
  atomicAdd(&svec[hd], ex);
}

// ---------------------------------------------------------------------------
// K6: out[head] += (evec[e]/svec[head]) * ent[tail]   (atomic scatter)
// ---------------------------------------------------------------------------
__global__ __launch_bounds__(256) void k_out(
    const float* __restrict__ ent, const int* __restrict__ head,
    const int* __restrict__ tail, const float* __restrict__ evec,
    const float* __restrict__ svec, float* __restrict__ out) {
  const int t = threadIdx.x;
  const int lane = t & 31;
  const int le = t >> 5;
  const int e = blockIdx.x * 8 + le;
  if (e >= N_EDGE) return;
  const int hd = head[e], tl = tail[e];
  const float soft = evec[e] / svec[hd];
  float4 x = *(const float4*)&ent[(size_t)tl * D + lane * 4];
  float* dst = out + (size_t)hd * D + lane * 4;
  atomicAdd(&dst[0], soft * x.x);
  atomicAdd(&dst[1], soft * x.y);
  atomicAdd(&dst[2], soft * x.z);
  atomicAdd(&dst[3], soft * x.w);
}

// ---------------------------------------------------------------------------
// Workspace layout (floats):
//   kg      [N_ENT*D]   = 12.8M   (memset 0)
//   attnorm [N_ENT*H]   =  0.4M   (memset 0)
//   mvec    [N_ENT]     =  0.1M   (memset 0; w>=0 so 0 == -inf here)
//   svec    [N_ENT]     =  0.1M   (memset 0)
//   expatt  [E*H]       =  1.6M
//   wvec    [E]         =  0.4M
//   evec    [E]         =  0.4M
// Total ~63.2 MB. Q lives in d_out (exactly N_ENT*D) until K2 finishes,
// then d_out is zeroed for the final scatter.
// ---------------------------------------------------------------------------
extern "C" void kernel_launch(void* const* d_in, const int* in_sizes, int n_in,
                              void* d_out, int out_size, void* d_ws,
                              size_t ws_size, hipStream_t stream) {
  const float* ent = (const float*)d_in[0];
  const float* wrel = (const float*)d_in[3];
  const float* qT = (const float*)d_in[4];
  const float* kT = (const float*)d_in[5];
  const float* vT = (const float*)d_in[6];
  const int* eidx = (const int*)d_in[7];
  const int* etype = (const int*)d_in[8];
  const int* head = eidx;
  const int* tail = eidx + N_EDGE;

  float* kg = (float*)d_ws;
  float* attnorm = kg + (size_t)N_ENT * D;
  unsigned int* mvec = (unsigned int*)(attnorm + (size_t)N_ENT * H);
  float* svec = (float*)(mvec + N_ENT);
  float* expatt = svec + N_ENT;
  float* wvec = expatt + (size_t)N_EDGE * H;
  float* evec = wvec + N_EDGE;
  float* Q = (float*)d_out;

  // zero kg, attnorm, mvec, svec in one contiguous memset
  const size_t zero_bytes =
      ((size_t)N_ENT * D + (size_t)N_ENT * H + 2 * (size_t)N_ENT) *
      sizeof(float);
  hipMemsetAsync(d_ws, 0, zero_bytes, stream);

  k_qproj<<<(N_ENT + 127) / 128, 512, 0, stream>>>(ent, qT, Q);
  k_attlogit<<<N_EDGE / 128, 512, 0, stream>>>(ent, wrel, kT, Q, head, tail,
                                               etype, expatt, attnorm);
  hipMemsetAsync(d_out, 0, (size_t)N_ENT * D * sizeof(float), stream);
  k_vagg<<<N_EDGE / 128, 512, 0, stream>>>(ent, wrel, vT, head, tail, etype,
                                           expatt, attnorm, kg);
  k_w<<<N_EDGE / 8, 256, 0, stream>>>(kg, wrel, head, tail, etype, wvec, mvec);
  k_expw<<<(N_EDGE + 255) / 256, 256, 0, stream>>>(head, wvec, mvec, evec,
                                                   svec);
  k_out<<<N_EDGE / 8, 256, 0, stream>>>(ent, head, tail, evec, svec,
                                        (float*)d_out);
}

// Round 3
// 1353.305 us; speedup vs baseline: 1.9402x; 1.9402x over previous
//
#include <hip/hip_runtime.h>
#include <cstdint>

#define D 128
#define H 4
#define N_ENT 100000
#define N_EDGE 400000
#define R 32

// ---------------------------------------------------------------------------
// CSR build: histogram -> single-block scan -> scatter (permuted tail/etype).
// ---------------------------------------------------------------------------
__global__ void k_hist(const int* __restrict__ head, int* __restrict__ deg) {
  const int e = blockIdx.x * 256 + threadIdx.x;
  if (e < N_EDGE) atomicAdd(&deg[head[e]], 1);
}

__global__ __launch_bounds__(1024) void k_scan(const int* __restrict__ deg,
                                               int* __restrict__ off,
                                               int* __restrict__ cur) {
  __shared__ int part[1024];
  const int t = threadIdx.x;
  const int CH = (N_ENT + 1023) / 1024;  // 98
  const int lo = t * CH;
  const int hi = (lo + CH < N_ENT) ? lo + CH : N_ENT;
  int s = 0;
  for (int i = lo; i < hi; ++i) s += deg[i];
  part[t] = s;
  __syncthreads();
  for (int d = 1; d < 1024; d <<= 1) {
    int v = (t >= d) ? part[t - d] : 0;
    __syncthreads();
    part[t] += v;
    __syncthreads();
  }
  int base = (t == 0) ? 0 : part[t - 1];
  for (int i = lo; i < hi; ++i) {
    const int dv = deg[i];
    off[i] = base;
    cur[i] = base;
    base += dv;
  }
  if (t == 0) off[N_ENT] = part[1023];
}

__global__ void k_scatter(const int* __restrict__ head,
                          const int* __restrict__ tail,
                          const int* __restrict__ etype, int* __restrict__ cur,
                          int* __restrict__ tailP, int* __restrict__ etypeP) {
  const int e = blockIdx.x * 256 + threadIdx.x;
  if (e >= N_EDGE) return;
  const int hd = head[e];
  const int pos = atomicAdd(&cur[hd], 1);
  tailP[pos] = tail[e];
  etypeP[pos] = etype[e] - 1;
}

// ---------------------------------------------------------------------------
// K1: Q = entity_emb @ qTrans   (Q stored in d_out; consumed & overwritten
// column-block-by-column-block by the 4 k_attagg passes)
// ---------------------------------------------------------------------------
__global__ __launch_bounds__(512) void k_qproj(const float* __restrict__ ent,
                                               const float* __restrict__ qT,
                                               float* __restrict__ Q) {
  __shared__ float sT[D * D];
  __shared__ float rows[D * 128];
  const int t = threadIdx.x;
  const int n0 = blockIdx.x * 128;
#pragma unroll
  for (int s = 0; s < 8; ++s) {
    const int idx = (s * 512 + t) * 4;
    *(float4*)&sT[idx] = *(const float4*)&qT[idx];
  }
  {
    const int g = t & 3;
    const int n = t >> 2;
    const int node = n0 + n;
    if (node < N_ENT) {
      const float* src = ent + (size_t)node * D;
#pragma unroll
      for (int s = 0; s < 8; ++s) {
        const int i = s * 16 + g * 4;
        float4 v = *(const float4*)&src[i];
        rows[(i + 0) * 128 + n] = v.x;
        rows[(i + 1) * 128 + n] = v.y;
        rows[(i + 2) * 128 + n] = v.z;
        rows[(i + 3) * 128 + n] = v.w;
      }
    } else {
#pragma unroll
      for (int s = 0; s < 8; ++s) {
        const int i = s * 16 + g * 4;
        rows[(i + 0) * 128 + n] = 0.f;
        rows[(i + 1) * 128 + n] = 0.f;
        rows[(i + 2) * 128 + n] = 0.f;
        rows[(i + 3) * 128 + n] = 0.f;
      }
    }
  }
  __syncthreads();
  const int jj = t & 15;
  const int ee = t >> 4;
  float acc[4][8];
#pragma unroll
  for (int a = 0; a < 4; ++a)
#pragma unroll
    for (int b = 0; b < 8; ++b) acc[a][b] = 0.f;
#pragma unroll 4
  for (int i = 0; i < D; ++i) {
    float4 b0 = *(float4*)&sT[i * D + jj * 8];
    float4 b1 = *(float4*)&sT[i * D + jj * 8 + 4];
    float4 a0 = *(float4*)&rows[i * 128 + ee * 4];
    float bv[8] = {b0.x, b0.y, b0.z, b0.w, b1.x, b1.y, b1.z, b1.w};
    float av[4] = {a0.x, a0.y, a0.z, a0.w};
#pragma unroll
    for (int a = 0; a < 4; ++a)
#pragma unroll
      for (int b = 0; b < 8; ++b) acc[a][b] = fmaf(av[a], bv[b], acc[a][b]);
  }
#pragma unroll
  for (int a = 0; a < 4; ++a) {
    const int node = n0 + ee * 4 + a;
    if (node < N_ENT) {
      float4 o0 = {acc[a][0], acc[a][1], acc[a][2], acc[a][3]};
      float4 o1 = {acc[a][4], acc[a][5], acc[a][6], acc[a][7]};
      *(float4*)&Q[(size_t)node * D + jj * 8] = o0;
      *(float4*)&Q[(size_t)node * D + jj * 8 + 4] = o1;
    }
  }
}

// ---------------------------------------------------------------------------
// K2 (x4, one per head h): fully fused per-node attention for head h.
// One wave per node n:
//   1. P[i] = sum_j kT[i,32h+j] * Q[n,32h+j]        (kT_h slab in LDS)
//   2. edge loop (2 edges/iter): nh = ent[tail]*wrel[ty];
//      logit = nh . P (shfl-reduce over 32 lanes); el = exp(clip(logit));
//      agg += el*nh; ssum += el
//   3. agg /= (ssum + 1e-8)
//   4. kg[n,32h+c] = sum_d agg[d] * vT[d,32h+c]     (vT_h slab in LDS)
// qkg = d_out: Q cols [32h,32h+32) read at start, kg written to the same
// cols at the end (only node n's wave touches row n). 32 KB LDS -> 5 blk/CU.
// ---------------------------------------------------------------------------
__global__ __launch_bounds__(256) void k_attagg(
    const float* __restrict__ ent, const float* __restrict__ wrel,
    const float* __restrict__ kT, const float* __restrict__ vT, float* qkg,
    const int* __restrict__ off, const int* __restrict__ tailP,
    const int* __restrict__ etypeP, const int h) {
  __shared__ float sKT[32 * 128];  // sKT[j][i] = kT[i, 32h+j]
  __shared__ float sVT[128 * 32];  // sVT[d][c] = vT[d, 32h+c]
  const int t = threadIdx.x;
  {  // load kT_h slab: thread t -> row i = t&127, col half hf = t>>7
    const int i = t & 127;
    const int hf = t >> 7;
    const float* kr = kT + (size_t)i * D + h * 32 + hf * 16;
#pragma unroll
    for (int s = 0; s < 4; ++s) {
      float4 v = *(const float4*)&kr[s * 4];
      const int j = hf * 16 + s * 4;
      sKT[(j + 0) * 128 + i] = v.x;
      sKT[(j + 1) * 128 + i] = v.y;
      sKT[(j + 2) * 128 + i] = v.z;
      sKT[(j + 3) * 128 + i] = v.w;
    }
  }
  {  // load vT_h slab row-major: thread t -> d = t>>1, c-half = (t&1)*16
    const int d = t >> 1;
    const int c0 = (t & 1) * 16;
    const float* vr = vT + (size_t)d * D + h * 32 + c0;
#pragma unroll
    for (int s = 0; s < 4; ++s)
      *(float4*)&sVT[d * 32 + c0 + s * 4] = *(const float4*)&vr[s * 4];
  }
  __syncthreads();

  const int wid = t >> 6;
  const int lane = t & 63;
  const int half = lane >> 5;
  const int l32 = lane & 31;
  const int n = blockIdx.x * 4 + wid;
  if (n >= N_ENT) return;

  // 1. P row for this node (replicated in both halves; lane holds i=l32*4..+3)
  const float qv = qkg[(size_t)n * D + h * 32 + l32];
  float4 Pv = {0.f, 0.f, 0.f, 0.f};
#pragma unroll
  for (int j = 0; j < 32; ++j) {
    const float qj = __shfl(qv, j);
    const float4 kt = *(const float4*)&sKT[j * 128 + l32 * 4];
    Pv.x = fmaf(qj, kt.x, Pv.x);
    Pv.y = fmaf(qj, kt.y, Pv.y);
    Pv.z = fmaf(qj, kt.z, Pv.z);
    Pv.w = fmaf(qj, kt.w, Pv.w);
  }

  // 2. edge loop, 2 edges in flight (half 0 / half 1)
  float4 agg = {0.f, 0.f, 0.f, 0.f};
  float ssum = 0.f;
  const int eb = off[n];
  const int deg = off[n + 1] - eb;
  for (int b = 0; b < deg; b += 2) {
    const int idx = b + half;
    const bool val = idx < deg;
    const int e = eb + (val ? idx : 0);
    const int tl = tailP[e];
    const int ty = etypeP[e];
    const float4 x = *(const float4*)&ent[(size_t)tl * D + l32 * 4];
    const float4 r = *(const float4*)&wrel[(size_t)ty * D + l32 * 4];
    const float4 nh = {x.x * r.x, x.y * r.y, x.z * r.z, x.w * r.w};
    float d0 = nh.x * Pv.x + nh.y * Pv.y + nh.z * Pv.z + nh.w * Pv.w;
#pragma unroll
    for (int k = 1; k < 32; k <<= 1) d0 += __shfl_xor(d0, k);
    const float el = val ? expf(fminf(fmaxf(d0, -10.f), 10.f)) : 0.f;
    agg.x = fmaf(el, nh.x, agg.x);
    agg.y = fmaf(el, nh.y, agg.y);
    agg.z = fmaf(el, nh.z, agg.z);
    agg.w = fmaf(el, nh.w, agg.w);
    ssum += el;
  }
  // combine the two halves
  agg.x += __shfl_xor(agg.x, 32);
  agg.y += __shfl_xor(agg.y, 32);
  agg.z += __shfl_xor(agg.z, 32);
  agg.w += __shfl_xor(agg.w, 32);
  ssum += __shfl_xor(ssum, 32);

  // 3. normalize
  const float inv = 1.f / (ssum + 1e-8f);
  agg.x *= inv;
  agg.y *= inv;
  agg.z *= inv;
  agg.w *= inv;

  // 4. project through vT_h: col c = l32; half handles d in [half*64, +64)
  float acc = 0.f;
  const int dbase = half * 64;
#pragma unroll
  for (int g = 0; g < 16; ++g) {
    const int d = dbase + g * 4;
    const int src = d >> 2;  // lane (0..31) holding agg[d..d+3]
    const float ax = __shfl(agg.x, src);
    const float ay = __shfl(agg.y, src);
    const float az = __shfl(agg.z, src);
    const float aw = __shfl(agg.w, src);
    acc = fmaf(ax, sVT[(d + 0) * 32 + l32], acc);
    acc = fmaf(ay, sVT[(d + 1) * 32 + l32], acc);
    acc = fmaf(az, sVT[(d + 2) * 32 + l32], acc);
    acc = fmaf(aw, sVT[(d + 3) * 32 + l32], acc);
  }
  acc += __shfl_xor(acc, 32);
  if (half == 0) qkg[(size_t)n * D + h * 32 + l32] = acc;  // kg overwrites Q_h
}

// ---------------------------------------------------------------------------
// K3: S[n,r] = sum_d kg[n,d]^2 * wrel[r,d]^2  (w(e) = S[head,ty]*S[tail,ty])
// ---------------------------------------------------------------------------
__global__ __launch_bounds__(256) void k_S(const float* __restrict__ kg,
                                           const float* __restrict__ wrel,
                                           float* __restrict__ S) {
  __shared__ float sB[D * 32];  // sB[d][r] = wrel[r][d]^2
  __shared__ float sA[D * 64];  // sA[d][n] = kg[n][d]^2
  const int t = threadIdx.x;
  const int n0 = blockIdx.x * 64;
  {
    const int r = t & 31;
    const int qg = t >> 5;  // 0..7
#pragma unroll
    for (int s = 0; s < 4; ++s) {
      const int d = qg * 16 + s * 4;
      float4 b = *(const float4*)&wrel[(size_t)r * D + d];
      sB[(d + 0) * 32 + r] = b.x * b.x;
      sB[(d + 1) * 32 + r] = b.y * b.y;
      sB[(d + 2) * 32 + r] = b.z * b.z;
      sB[(d + 3) * 32 + r] = b.w * b.w;
    }
  }
  {
    const int nn = t & 63;
    const int dg = t >> 6;
    const int node = n0 + nn;
#pragma unroll
    for (int s = 0; s < 8; ++s) {
      const int d = dg * 32 + s * 4;
      float4 a = {0, 0, 0, 0};
      if (node < N_ENT) a = *(const float4*)&kg[(size_t)node * D + d];
      sA[(d + 0) * 64 + nn] = a.x * a.x;
      sA[(d + 1) * 64 + nn] = a.y * a.y;
      sA[(d + 2) * 64 + nn] = a.z * a.z;
      sA[(d + 3) * 64 + nn] = a.w * a.w;
    }
  }
  __syncthreads();
  const int nn2 = t >> 2;
  const int rg = t & 3;
  float acc[8];
#pragma unroll
  for (int c = 0; c < 8; ++c) acc[c] = 0.f;
#pragma unroll 4
  for (int d = 0; d < D; ++d) {
    const float a = sA[d * 64 + nn2];
    float4 b0 = *(float4*)&sB[d * 32 + rg * 8];
    float4 b1 = *(float4*)&sB[d * 32 + rg * 8 + 4];
    acc[0] = fmaf(a, b0.x, acc[0]);
    acc[1] = fmaf(a, b0.y, acc[1]);
    acc[2] = fmaf(a, b0.z, acc[2]);
    acc[3] = fmaf(a, b0.w, acc[3]);
    acc[4] = fmaf(a, b1.x, acc[4]);
    acc[5] = fmaf(a, b1.y, acc[5]);
    acc[6] = fmaf(a, b1.z, acc[6]);
    acc[7] = fmaf(a, b1.w, acc[7]);
  }
  const int node = n0 + nn2;
  if (node < N_ENT) {
    float4 o0 = {acc[0], acc[1], acc[2], acc[3]};
    float4 o1 = {acc[4], acc[5], acc[6], acc[7]};
    *(float4*)&S[(size_t)node * 32 + rg * 8] = o0;
    *(float4*)&S[(size_t)node * 32 + rg * 8 + 4] = o1;
  }
}

// ---------------------------------------------------------------------------
// K4: per-node online softmax over w(e)=S[n,ty]*S[tail,ty] + weighted gather.
// One wave per node; no atomics. Writes the final output (overwrites d_out).
// ---------------------------------------------------------------------------
__global__ __launch_bounds__(256) void k_out2(
    const float* __restrict__ ent, const float* __restrict__ S,
    const int* __restrict__ off, const int* __restrict__ tailP,
    const int* __restrict__ etypeP, float* __restrict__ out) {
  const int t = threadIdx.x;
  const int wid = t >> 6;
  const int lane = t & 63;
  const int n = blockIdx.x * 4 + wid;
  if (n >= N_ENT) return;
  const int eb = off[n];
  const int deg = off[n + 1] - eb;
  float accx = 0.f, accy = 0.f;
  float m = 0.f, ssum = 0.f;
  for (int b = 0; b < deg; b += 64) {
    const int idx = b + lane;
    const bool val = idx < deg;
    const int e = eb + (val ? idx : 0);
    const int tl = tailP[e];
    const int ty = etypeP[e];
    float w = val ? S[(size_t)n * 32 + ty] * S[(size_t)tl * 32 + ty] : -1.f;
    float cm = w;
#pragma unroll
    for (int k = 1; k < 64; k <<= 1) cm = fmaxf(cm, __shfl_xor(cm, k));
    const float mnew = fmaxf(m, cm);
    const float scale = expf(m - mnew);
    const float el = val ? expf(w - mnew) : 0.f;
    float cs = el;
#pragma unroll
    for (int k = 1; k < 64; k <<= 1) cs += __shfl_xor(cs, k);
    ssum = ssum * scale + cs;
    accx *= scale;
    accy *= scale;
    const int cnt = (deg - b < 64) ? deg - b : 64;
    for (int j = 0; j < cnt; ++j) {
      const float sj = __shfl(el, j);
      const int tlj = __shfl(tl, j);
      const float2 x = *(const float2*)&ent[(size_t)tlj * D + lane * 2];
      accx = fmaf(sj, x.x, accx);
      accy = fmaf(sj, x.y, accy);
    }
    m = mnew;
  }
  const float inv = (deg > 0) ? 1.f / ssum : 0.f;
  float2 o = {accx * inv, accy * inv};
  *(float2*)&out[(size_t)n * D + lane * 2] = o;
}

// ---------------------------------------------------------------------------
// Workspace (17.2 MB total — round 1's 63.2 MB worked, round 2's 273 MB
// crashed, so stay small):
//   S      [N*32] fp32  = 12.8 MB
//   off    [N+1] int, cur [N] int, deg [N] int
//   tailP  [E] int, etypeP [E] int
// d_out timeline: Q (k_qproj) -> kg (4x k_attagg, column block per head)
//                 -> final output (k_out2). Only memset: deg (0.4 MB).
// ---------------------------------------------------------------------------
extern "C" void kernel_launch(void* const* d_in, const int* in_sizes, int n_in,
                              void* d_out, int out_size, void* d_ws,
                              size_t ws_size, hipStream_t stream) {
  const float* ent = (const float*)d_in[0];
  const float* wrel = (const float*)d_in[3];
  const float* qT = (const float*)d_in[4];
  const float* kT = (const float*)d_in[5];
  const float* vT = (const float*)d_in[6];
  const int* eidx = (const int*)d_in[7];
  const int* etype = (const int*)d_in[8];
  const int* head = eidx;
  const int* tail = eidx + N_EDGE;

  float* S = (float*)d_ws;
  int* off = (int*)(S + (size_t)N_ENT * 32);
  int* cur = off + (N_ENT + 1);
  int* deg = cur + N_ENT;
  int* tailP = deg + N_ENT;
  int* etypeP = tailP + N_EDGE;
  float* qkg = (float*)d_out;

  hipMemsetAsync(deg, 0, N_ENT * sizeof(int), stream);
  k_hist<<<(N_EDGE + 255) / 256, 256, 0, stream>>>(head, deg);
  k_scan<<<1, 1024, 0, stream>>>(deg, off, cur);
  k_scatter<<<(N_EDGE + 255) / 256, 256, 0, stream>>>(head, tail, etype, cur,
                                                      tailP, etypeP);
  k_qproj<<<(N_ENT + 127) / 128, 512, 0, stream>>>(ent, qT, qkg);
  for (int h = 0; h < H; ++h) {
    k_attagg<<<(N_ENT + 3) / 4, 256, 0, stream>>>(ent, wrel, kT, vT, qkg, off,
                                                  tailP, etypeP, h);
  }
  k_S<<<(N_ENT + 63) / 64, 256, 0, stream>>>(qkg, wrel, S);
  k_out2<<<(N_ENT + 3) / 4, 256, 0, stream>>>(ent, S, off, tailP, etypeP,
                                              qkg);
}